// Round 6
// baseline (121.693 us; speedup 1.0000x reference)
//
#include <hip/hip_runtime.h>

// Problem shape (fixed by setup_inputs): B=8192 rows, C=4096 cols, fp32.
#define B_ROWS 8192
#define C_COLS 4096

typedef float fv4 __attribute__((ext_vector_type(4)));  // native vec for builtins

__device__ __forceinline__ float wave_reduce_sum(float v) {
    #pragma unroll
    for (int o = 32; o > 0; o >>= 1) v += __shfl_down(v, o, 64);
    return v;
}

// One block per row. Identities used:
//   eu = e^{(1-2y)x}  (= e^x if y==0, e^{-x} if y==1) serves the corr sums AND
//   BCE elem: max(x,0)-xy+log1p(e^{-|x|}) == log(1+eu)
//   s_neg = sum_{y==0} e^x = sum(eu) - sum(y*eu)
// y is loaded non-temporally (nt) so x (134 MB) stays resident in the 256 MiB
// L3 across graph replays; only y streams from HBM.
__global__ __launch_bounds__(256) void row_stage(const float* __restrict__ x,
                                                 const float* __restrict__ y,
                                                 float* __restrict__ out) {
    const int row = blockIdx.x;
    const size_t base = (size_t)row * C_COLS;
    const fv4* x4 = reinterpret_cast<const fv4*>(x + base);
    const fv4* y4 = reinterpret_cast<const fv4*>(y + base);

    const float LOG2E   = 1.44269504088896340736f;
    const float N2LOG2E = -2.0f * 1.44269504088896340736f;
    const float LN2     = 0.69314718055994530942f;

    // Preload the whole per-thread slice: 8 dwordx4 loads in flight (MLP).
    fv4 xr[4], yr[4];
    #pragma unroll
    for (int it = 0; it < 4; ++it) {
        const int i = it * 256 + threadIdx.x;   // 1024 float4 per row
        xr[it] = x4[i];
        yr[it] = __builtin_nontemporal_load(&y4[i]);
    }

    float s_all = 0.f, s_pos = 0.f, bce = 0.f, n1 = 0.f;

    #pragma unroll
    for (int it = 0; it < 4; ++it) {
        float prod = 1.0f;
        #pragma unroll
        for (int k = 0; k < 4; ++k) {
            float xx = xr[it][k];
            float yy = yr[it][k];                    // exactly 0.0f or 1.0f
            float m  = fmaf(N2LOG2E, yy, LOG2E);     // (1-2y)*log2(e)
            float eu = __builtin_amdgcn_exp2f(xx * m);  // e^{(1-2y)x} <= ~400
            s_all = s_all + eu;
            s_pos = fmaf(yy, eu, s_pos);             // sum_{y==1} e^{-x}
            n1   += yy;
            prod  = fmaf(prod, eu, prod);            // prod *= (1 + eu)
        }
        // sum of log(1+eu) over 4 elems; prod <= ~2.6e10, safe in fp32
        bce = fmaf(LN2, __builtin_amdgcn_logf(prod), bce);
    }

    // Block reduction: wave shuffle then LDS across the 4 waves.
    float a = wave_reduce_sum(s_all);
    float b = wave_reduce_sum(s_pos);
    float c = wave_reduce_sum(bce);
    float d = wave_reduce_sum(n1);

    __shared__ float red[4][4];
    const int lane = threadIdx.x & 63;
    const int wid  = threadIdx.x >> 6;
    if (lane == 0) {
        red[wid][0] = a; red[wid][1] = b; red[wid][2] = c; red[wid][3] = d;
    }
    __syncthreads();

    if (threadIdx.x == 0) {
        float SA = red[0][0] + red[1][0] + red[2][0] + red[3][0];
        float SP = red[0][1] + red[1][1] + red[2][1] + red[3][1];
        float BC = red[0][2] + red[1][2] + red[2][2] + red[3][2];
        float N1 = red[0][3] + red[1][3] + red[2][3] + red[3][3];
        float SN = SA - SP;                          // sum_{y==0} e^{x}
        float N0 = (float)C_COLS - N1;
        float denom = N0 * N1;
        float per_row = (denom > 0.f) ? (SN * SP) / denom : 0.f;
        float contrib = BC * (1.0f / ((float)B_ROWS * (float)C_COLS))
                      + per_row * (1.0f / (float)B_ROWS);
        // 8192 single atomics to one address: negligible contention, no
        // fences (R3's per-block __threadfence was the 20x regression).
        atomicAdd(out, contrib);
    }
}

extern "C" void kernel_launch(void* const* d_in, const int* in_sizes, int n_in,
                              void* d_out, int out_size, void* d_ws, size_t ws_size,
                              hipStream_t stream) {
    const float* x = (const float*)d_in[0];  // y_hat, fp32 [8192, 4096]
    const float* y = (const float*)d_in[1];  // y,     fp32 [8192, 4096]
    float* out = (float*)d_out;              // scalar fp32

    (void)hipMemsetAsync(out, 0, sizeof(float), stream);  // graph-capturable
    row_stage<<<B_ROWS, 256, 0, stream>>>(x, y, out);
}

// Round 7
// 121.225 us; speedup vs baseline: 1.0039x; 1.0039x over previous
//
#include <hip/hip_runtime.h>

// Problem shape (fixed by setup_inputs): B=8192 rows, C=4096 cols, fp32.
#define B_ROWS 8192
#define C_COLS 4096

typedef float fv4 __attribute__((ext_vector_type(4)));

__device__ __forceinline__ float wave_reduce_sum(float v) {
    #pragma unroll
    for (int o = 32; o > 0; o >>= 1) v += __shfl_down(v, o, 64);
    return v;
}

// One block per row. Identities:
//   eu = e^{(1-2y)x}  (= e^x if y==0, e^{-x} if y==1) serves the corr sums AND
//   BCE elem: max(x,0)-xy+log1p(e^{-|x|}) == log(1+eu)
//   s_neg = sum_{y==0} e^x = sum(eu) - sum(y*eu)
// NOTE (R6 lesson): __builtin_nontemporal_load here was a 2.4x regression —
// nt bypasses cache allocation and goes latency-bound. Plain loads.
__global__ __launch_bounds__(256) void row_stage(const float* __restrict__ x,
                                                 const float* __restrict__ y,
                                                 float* __restrict__ out) {
    const int row = blockIdx.x;
    const size_t base = (size_t)row * C_COLS;
    const fv4* x4 = reinterpret_cast<const fv4*>(x + base);
    const fv4* y4 = reinterpret_cast<const fv4*>(y + base);

    const float LOG2E   = 1.44269504088896340736f;
    const float N2LOG2E = -2.0f * 1.44269504088896340736f;
    const float LN2     = 0.69314718055994530942f;

    // Preload the per-thread slice (8 dwordx4 in flight if the compiler
    // honors it — check VGPR count).
    fv4 xr[4], yr[4];
    #pragma unroll
    for (int it = 0; it < 4; ++it) {
        const int i = it * 256 + threadIdx.x;   // 1024 float4 per row
        xr[it] = x4[i];
        yr[it] = y4[i];
    }

    float s_all = 0.f, s_pos = 0.f, bce = 0.f, n1 = 0.f;

    #pragma unroll
    for (int it = 0; it < 4; ++it) {
        float prod = 1.0f;
        #pragma unroll
        for (int k = 0; k < 4; ++k) {
            float xx = xr[it][k];
            float yy = yr[it][k];                    // exactly 0.0f or 1.0f
            float m  = fmaf(N2LOG2E, yy, LOG2E);     // (1-2y)*log2(e)
            float eu = __builtin_amdgcn_exp2f(xx * m);  // e^{(1-2y)x} <= ~400
            s_all = s_all + eu;
            s_pos = fmaf(yy, eu, s_pos);             // sum_{y==1} e^{-x}
            n1   += yy;
            prod  = fmaf(prod, eu, prod);            // prod *= (1 + eu)
        }
        // sum of log(1+eu) over 4 elems; prod <= ~2.6e10, safe in fp32
        bce = fmaf(LN2, __builtin_amdgcn_logf(prod), bce);
    }

    // Block reduction: wave shuffle then LDS across the 4 waves.
    float a = wave_reduce_sum(s_all);
    float b = wave_reduce_sum(s_pos);
    float c = wave_reduce_sum(bce);
    float d = wave_reduce_sum(n1);

    __shared__ float red[4][4];
    const int lane = threadIdx.x & 63;
    const int wid  = threadIdx.x >> 6;
    if (lane == 0) {
        red[wid][0] = a; red[wid][1] = b; red[wid][2] = c; red[wid][3] = d;
    }
    __syncthreads();

    if (threadIdx.x == 0) {
        float SA = red[0][0] + red[1][0] + red[2][0] + red[3][0];
        float SP = red[0][1] + red[1][1] + red[2][1] + red[3][1];
        float BC = red[0][2] + red[1][2] + red[2][2] + red[3][2];
        float N1 = red[0][3] + red[1][3] + red[2][3] + red[3][3];
        float SN = SA - SP;                          // sum_{y==0} e^{x}
        float N0 = (float)C_COLS - N1;
        float denom = N0 * N1;
        float per_row = (denom > 0.f) ? (SN * SP) / denom : 0.f;
        float contrib = BC * (1.0f / ((float)B_ROWS * (float)C_COLS))
                      + per_row * (1.0f / (float)B_ROWS);
        // One atomic per block to a single address: ~8192 total, staggered by
        // block completion — negligible contention, no device fences.
        atomicAdd(out, contrib);
    }
}

extern "C" void kernel_launch(void* const* d_in, const int* in_sizes, int n_in,
                              void* d_out, int out_size, void* d_ws, size_t ws_size,
                              hipStream_t stream) {
    const float* x = (const float*)d_in[0];  // y_hat, fp32 [8192, 4096]
    const float* y = (const float*)d_in[1];  // y,     fp32 [8192, 4096]
    float* out = (float*)d_out;              // scalar fp32

    (void)hipMemsetAsync(out, 0, sizeof(float), stream);  // graph-capturable
    row_stage<<<B_ROWS, 256, 0, stream>>>(x, y, out);
}

// Round 8
// 44.702 us; speedup vs baseline: 2.7223x; 2.7118x over previous
//
#include <hip/hip_runtime.h>

// Problem shape (fixed by setup_inputs): B=8192 rows, C=4096 cols, fp32.
#define B_ROWS 8192
#define C_COLS 4096

typedef float fv4 __attribute__((ext_vector_type(4)));

__device__ __forceinline__ float wave_reduce_sum(float v) {
    #pragma unroll
    for (int o = 32; o > 0; o >>= 1) v += __shfl_down(v, o, 64);
    return v;
}

// One block per row. Identities:
//   eu = e^{(1-2y)x}  (= e^x if y==0, e^{-x} if y==1) serves the corr sums AND
//   BCE elem: max(x,0)-xy+log1p(e^{-|x|}) == log(1+eu)
//   s_neg = sum_{y==0} e^x = sum(eu) - sum(y*eu)
// Structure notes (hard-won):
//   R3: per-block __threadfence -> 20x regression (per-block L2 writeback).
//   R6/R7: single-address atomicAdd tail + memset graph node -> 2.4x
//          regression (atomic serialization + lost warm-L3 across replays).
//   => plain per-row stores to scratch + separate tiny reduce kernel.
__global__ __launch_bounds__(256) void row_stage(const float* __restrict__ x,
                                                 const float* __restrict__ y,
                                                 float* __restrict__ row_out) {
    const int row = blockIdx.x;
    const size_t base = (size_t)row * C_COLS;
    const fv4* x4 = reinterpret_cast<const fv4*>(x + base);
    const fv4* y4 = reinterpret_cast<const fv4*>(y + base);

    const float LOG2E   = 1.44269504088896340736f;
    const float N2LOG2E = -2.0f * 1.44269504088896340736f;
    const float LN2     = 0.69314718055994530942f;

    float s_all = 0.f, s_pos = 0.f, bce = 0.f, n1 = 0.f;

    #pragma unroll
    for (int it = 0; it < 4; ++it) {
        const int i = it * 256 + threadIdx.x;   // 1024 float4 per row
        fv4 xv = x4[i];
        fv4 yv = y4[i];
        float prod = 1.0f;
        #pragma unroll
        for (int k = 0; k < 4; ++k) {
            float xx = xv[k];
            float yy = yv[k];                        // exactly 0.0f or 1.0f
            float m  = fmaf(N2LOG2E, yy, LOG2E);     // (1-2y)*log2(e)
            float eu = __builtin_amdgcn_exp2f(xx * m);  // e^{(1-2y)x} <= ~400
            s_all = s_all + eu;
            s_pos = fmaf(yy, eu, s_pos);             // sum_{y==1} e^{-x}
            n1   += yy;
            prod  = fmaf(prod, eu, prod);            // prod *= (1 + eu)
        }
        // sum of log(1+eu) over 4 elems; prod <= ~2.6e10, safe in fp32
        bce = fmaf(LN2, __builtin_amdgcn_logf(prod), bce);
    }

    // Block reduction: wave shuffle then LDS across the 4 waves.
    float a = wave_reduce_sum(s_all);
    float b = wave_reduce_sum(s_pos);
    float c = wave_reduce_sum(bce);
    float d = wave_reduce_sum(n1);

    __shared__ float red[4][4];
    const int lane = threadIdx.x & 63;
    const int wid  = threadIdx.x >> 6;
    if (lane == 0) {
        red[wid][0] = a; red[wid][1] = b; red[wid][2] = c; red[wid][3] = d;
    }
    __syncthreads();

    if (threadIdx.x == 0) {
        float SA = red[0][0] + red[1][0] + red[2][0] + red[3][0];
        float SP = red[0][1] + red[1][1] + red[2][1] + red[3][1];
        float BC = red[0][2] + red[1][2] + red[2][2] + red[3][2];
        float N1 = red[0][3] + red[1][3] + red[2][3] + red[3][3];
        float SN = SA - SP;                          // sum_{y==0} e^{x}
        float N0 = (float)C_COLS - N1;
        float denom = N0 * N1;
        float per_row = (denom > 0.f) ? (SN * SP) / denom : 0.f;
        row_out[row] = BC * (1.0f / ((float)B_ROWS * (float)C_COLS))
                     + per_row * (1.0f / (float)B_ROWS);
    }
}

// Single-block deterministic reduction of the 8192 row contributions.
__global__ __launch_bounds__(1024) void final_reduce(const float* __restrict__ row_vals,
                                                     float* __restrict__ out) {
    float s = 0.f;
    #pragma unroll
    for (int it = 0; it < 8; ++it) s += row_vals[it * 1024 + threadIdx.x];
    s = wave_reduce_sum(s);
    __shared__ float red[16];
    const int lane = threadIdx.x & 63;
    const int wid  = threadIdx.x >> 6;
    if (lane == 0) red[wid] = s;
    __syncthreads();
    if (threadIdx.x == 0) {
        float t = 0.f;
        #pragma unroll
        for (int w = 0; w < 16; ++w) t += red[w];
        out[0] = t;
    }
}

extern "C" void kernel_launch(void* const* d_in, const int* in_sizes, int n_in,
                              void* d_out, int out_size, void* d_ws, size_t ws_size,
                              hipStream_t stream) {
    const float* x = (const float*)d_in[0];  // y_hat, fp32 [8192, 4096]
    const float* y = (const float*)d_in[1];  // y,     fp32 [8192, 4096]
    float* out = (float*)d_out;              // scalar fp32
    float* row_vals = (float*)d_ws;          // 8192 floats of scratch

    row_stage<<<B_ROWS, 256, 0, stream>>>(x, y, row_vals);
    final_reduce<<<1, 1024, 0, stream>>>(row_vals, out);
}